// Round 6
// baseline (50.016 us; speedup 1.0000x reference)
//
#include <hip/hip_runtime.h>
#include <math.h>

#define LOG2E 1.4426950408889634f
#define NSLOT 512   // LDS window: atoms [key_base, key_base+512) per block
#define EPB   1024  // edges per block (256 threads x 4 edges)

// consts layout (7 floats):
//   [0]    softmax coeff of the min-exponent term (its exp factor == 1)
//   [1..3] softmax coeffs of the other 3 terms
//   [4..6] (e2_k - e2_min) / |a|   (log2-domain exponent deltas, pre-divided)
//
// ws layout: tabj float2[N] = (za, z)   j-side gather payload
//            za   float[N]              i-side exponent term (LDS-staged)
//            fi   float[N]  = 0.5*z*atom_mask   i-side factor (sweep-deferred)

// ---------------------------------------------------------------------------
// Kernel 1: per-atom tables, zero output, scalar consts.
// ---------------------------------------------------------------------------
__global__ __launch_bounds__(256) void zbl_prep_kernel(
    const float* __restrict__ z, const float* __restrict__ amask,
    const float* __restrict__ a_coef, const float* __restrict__ a_exp,
    const float* __restrict__ phi_c, const float* __restrict__ phi_e,
    float2* __restrict__ tabj, float* __restrict__ za, float* __restrict__ fi,
    float* __restrict__ out, float* __restrict__ consts, int n_atoms) {
  int n = blockIdx.x * blockDim.x + threadIdx.x;
  if (n < n_atoms) {
    float zi = z[n];                       // in [1, 94] -> log safe
    float ae = fabsf(a_exp[0]);
    float zan = __builtin_amdgcn_exp2f(ae * __builtin_amdgcn_logf(zi));
    tabj[n] = make_float2(zan, zi);
    za[n] = zan;
    fi[n] = 0.5f * zi * amask[n];
    out[n] = 0.0f;
  }
  if (blockIdx.x == 0 && threadIdx.x == 0) {
    float c[4], e2[4];
    float m = -1e30f;
    for (int k = 0; k < 4; ++k) { c[k] = fabsf(phi_c[k]); m = fmaxf(m, c[k]); }
    float s = 0.0f;
    for (int k = 0; k < 4; ++k) { c[k] = expf(c[k] - m); s += c[k]; }
    for (int k = 0; k < 4; ++k) c[k] /= s;
    int kmin = 0;
    for (int k = 0; k < 4; ++k) {
      e2[k] = fabsf(phi_e[k]) * LOG2E;
      if (e2[k] < e2[kmin]) kmin = k;
    }
    float inv_a = 1.0f / fabsf(a_coef[0]);
    consts[0] = c[kmin];
    int p = 1;
    for (int k = 0; k < 4; ++k) {
      if (k != kmin) {
        consts[p] = c[k];
        consts[3 + p] = (e2[k] - e2[kmin]) * inv_a;
        ++p;
      }
    }
  }
}

// ---------------------------------------------------------------------------
// Per-edge math (verified R3/R4/R5). za_i staged via LDS; i-side factor
// (0.5*z_i*amask_i) applied later at emission (exact by distributivity).
// tj = (za_j, z_j).
// ---------------------------------------------------------------------------
__device__ __forceinline__ float zbl_edge_value(
    float dx, float dy, float dz, float za_i, float2 tj, float bm,
    float c0, float c1, float c2, float c3,
    float dd1, float dd2, float dd3) {
  float n2 = fmaxf(dx * dx + dy * dy + dz * dz, 1e-20f);
  float r = __builtin_amdgcn_rsqf(n2);  // 1/d
  float d = n2 * r;                     // d = sqrt(n2)
  // smooth switch on [CUTON=4, CUTOFF=5]
  float x = 5.0f - d;
  float poly = ((6.0f * x - 15.0f) * x + 10.0f) * x * x * x;
  float sw = (d < 4.0f) ? 1.0f : ((d >= 5.0f) ? 0.0f : poly);
  float q = d * fmaxf(za_i + tj.x, 1e-10f);
  // phi = c_min + sum_k c_k * 2^(-dd_k*q)  (reference's shifted-exp quirk:
  // max_log = -e_min*arg is always the max term since arg >= 0)
  float phi = c0 + c1 * __builtin_amdgcn_exp2f(-dd1 * q)
                 + c2 * __builtin_amdgcn_exp2f(-dd2 * q)
                 + c3 * __builtin_amdgcn_exp2f(-dd3 * q);
  return tj.y * r * fmaxf(phi, 1e-30f) * fmaxf(sw, 1e-30f) * bm;
}

// ---------------------------------------------------------------------------
// Kernel 2: block owns 1024 consecutive edges (4/thread).
// Phase 1 (one flat VMEM batch, no deps): stage za/fi for the block's atom
//   window + all per-edge loads (idx, disp, bmask, j-gathers) into registers.
// Barrier. Phase 2: pure-ALU edge values (za_i from LDS), in-register run
//   merge, LDS-atomic accumulate by (key - key_base). Barrier. Phase 3:
//   sweep slots, one global atomic per touched atom, x fi (i-factor).
// Out-of-window keys fall back to global atomics (x fi[key]), so correctness
// never depends on sortedness.
// ---------------------------------------------------------------------------
__global__ __launch_bounds__(256, 8) void zbl_edge_kernel(
    const float* __restrict__ disp, const int* __restrict__ idx_i,
    const int* __restrict__ idx_j, const float* __restrict__ bmask,
    const float2* __restrict__ tabj, const float* __restrict__ za,
    const float* __restrict__ fi, const float* __restrict__ consts,
    float* __restrict__ out, int n_edges, int n_atoms) {
  __shared__ float acc[NSLOT];
  __shared__ float za_s[NSLOT];
  const int t = threadIdx.x;
  const long bb = (long)blockIdx.x * EPB;

  const int key_base = idx_i[bb];  // uniform broadcast load

  // ---- Phase 1: issue ALL global loads as one batch ----
  const int a0 = min(key_base + t, n_atoms - 1);
  const int a1 = min(key_base + t + 256, n_atoms - 1);
  const float zs0 = za[a0], zs1 = za[a1];   // window stage (coalesced)
  const float fi0 = fi[a0], fi1 = fi[a1];   // sweep factors (coalesced)

  const float c0 = consts[0], c1 = consts[1], c2 = consts[2], c3 = consts[3];
  const float dd1 = consts[4], dd2 = consts[5], dd3 = consts[6];

  const long L = (long)blockIdx.x * 256 + t;  // global quad id
  const long e0 = L * 4;

  // per-edge named registers (avoid runtime-indexed arrays -> scratch)
  int k0 = -1, k1 = -1, k2 = -1, k3 = -1;
  float d00 = 0.f, d01 = 0.f, d02 = 0.f, bm0 = 0.f;
  float d10 = 0.f, d11 = 0.f, d12 = 0.f, bm1 = 0.f;
  float d20 = 0.f, d21 = 0.f, d22 = 0.f, bm2 = 0.f;
  float d30 = 0.f, d31 = 0.f, d32 = 0.f, bm3 = 0.f;
  float2 tj0 = make_float2(0.f, 0.f), tj1 = tj0, tj2 = tj0, tj3 = tj0;

  if (e0 + 3 < (long)n_edges) {
    int4 I = ((const int4*)idx_i)[L];
    int4 J = ((const int4*)idx_j)[L];
    tj0 = tabj[J.x]; tj1 = tabj[J.y]; tj2 = tabj[J.z]; tj3 = tabj[J.w];
    const float4* d4 = (const float4*)disp;
    float4 A = d4[3 * L], B = d4[3 * L + 1], Cc = d4[3 * L + 2];
    float4 BM = ((const float4*)bmask)[L];
    // disp unpack: e0=(A.x,A.y,A.z) e1=(A.w,B.x,B.y) e2=(B.z,B.w,Cc.x)
    //              e3=(Cc.y,Cc.z,Cc.w)
    d00 = A.x;  d01 = A.y;  d02 = A.z;  bm0 = BM.x;
    d10 = A.w;  d11 = B.x;  d12 = B.y;  bm1 = BM.y;
    d20 = B.z;  d21 = B.w;  d22 = Cc.x; bm2 = BM.z;
    d30 = Cc.y; d31 = Cc.z; d32 = Cc.w; bm3 = BM.w;
    k0 = I.x; k1 = I.y; k2 = I.z; k3 = I.w;
  } else {
    long e;
    e = e0;
    if (e < (long)n_edges) {
      k0 = idx_i[e]; tj0 = tabj[idx_j[e]];
      d00 = disp[3 * e]; d01 = disp[3 * e + 1]; d02 = disp[3 * e + 2];
      bm0 = bmask[e];
    }
    e = e0 + 1;
    if (e < (long)n_edges) {
      k1 = idx_i[e]; tj1 = tabj[idx_j[e]];
      d10 = disp[3 * e]; d11 = disp[3 * e + 1]; d12 = disp[3 * e + 2];
      bm1 = bmask[e];
    }
    e = e0 + 2;
    if (e < (long)n_edges) {
      k2 = idx_i[e]; tj2 = tabj[idx_j[e]];
      d20 = disp[3 * e]; d21 = disp[3 * e + 1]; d22 = disp[3 * e + 2];
      bm2 = bmask[e];
    }
    e = e0 + 3;
    if (e < (long)n_edges) {
      k3 = idx_i[e]; tj3 = tabj[idx_j[e]];
      d30 = disp[3 * e]; d31 = disp[3 * e + 1]; d32 = disp[3 * e + 2];
      bm3 = bmask[e];
    }
  }

  // LDS init + window stage (za loads already issued above)
  acc[t] = 0.0f;
  acc[t + 256] = 0.0f;
  za_s[t] = zs0;
  za_s[t + 256] = zs1;
  __syncthreads();

  // ---- Phase 2: pure-ALU compute + reduce ----
  auto za_i = [&](int i) -> float {
    if (i < 0) return 0.0f;
    int s = i - key_base;
    if ((unsigned)s < (unsigned)NSLOT) return za_s[s];
    return za[i];  // out-of-window fallback (never taken for sorted idx_i)
  };

  float v0 = (k0 >= 0) ? zbl_edge_value(d00, d01, d02, za_i(k0), tj0, bm0,
                                        c0, c1, c2, c3, dd1, dd2, dd3) : 0.f;
  float v1 = (k1 >= 0) ? zbl_edge_value(d10, d11, d12, za_i(k1), tj1, bm1,
                                        c0, c1, c2, c3, dd1, dd2, dd3) : 0.f;
  float v2 = (k2 >= 0) ? zbl_edge_value(d20, d21, d22, za_i(k2), tj2, bm2,
                                        c0, c1, c2, c3, dd1, dd2, dd3) : 0.f;
  float v3 = (k3 >= 0) ? zbl_edge_value(d30, d31, d32, za_i(k3), tj3, bm3,
                                        c0, c1, c2, c3, dd1, dd2, dd3) : 0.f;

  auto flush = [&](int key, float s) {
    if (key < 0) return;
    int slot = key - key_base;
    if ((unsigned)slot < (unsigned)NSLOT) atomicAdd(&acc[slot], s);
    else atomicAdd(&out[key], s * fi[key]);  // rare fallback
  };

  {  // in-register merge of equal-adjacent keys (sorted => ~1 run per thread)
    int cur = k0;
    float s = v0;
    if (k1 == cur) s += v1; else { flush(cur, s); cur = k1; s = v1; }
    if (k2 == cur) s += v2; else { flush(cur, s); cur = k2; s = v2; }
    if (k3 == cur) s += v3; else { flush(cur, s); cur = k3; s = v3; }
    flush(cur, s);
  }

  __syncthreads();  // all LDS accumulation done

  // ---- Phase 3: sweep (fi factors preloaded in phase 1) ----
  {
    float val = acc[t];
    if (val != 0.0f) atomicAdd(&out[key_base + t], val * fi0);
    val = acc[t + 256];
    if (val != 0.0f) atomicAdd(&out[key_base + t + 256], val * fi1);
  }
}

extern "C" void kernel_launch(void* const* d_in, const int* in_sizes, int n_in,
                              void* d_out, int out_size, void* d_ws,
                              size_t ws_size, hipStream_t stream) {
  const float* atomic_numbers = (const float*)d_in[0];
  const float* disp           = (const float*)d_in[1];
  const int*   idx_i          = (const int*)d_in[2];
  const int*   idx_j          = (const int*)d_in[3];
  const float* atom_mask      = (const float*)d_in[4];
  // d_in[5] = batch_segments (unused), d_in[7] = batch_size (unused)
  const float* bmask          = (const float*)d_in[6];
  const float* a_coef         = (const float*)d_in[8];
  const float* a_exp          = (const float*)d_in[9];
  const float* phi_c          = (const float*)d_in[10];
  const float* phi_e          = (const float*)d_in[11];

  int n_atoms = in_sizes[0];
  int n_edges = in_sizes[2];

  float* out = (float*)d_out;
  float2* tabj = (float2*)d_ws;
  float*  zaw  = (float*)((char*)d_ws + (size_t)n_atoms * sizeof(float2));
  float*  fiw  = zaw + n_atoms;
  float*  consts = fiw + n_atoms;

  int atom_blocks = (n_atoms + 255) / 256;
  int edge_blocks = (int)(((long)n_edges + EPB - 1) / EPB);

  zbl_prep_kernel<<<atom_blocks, 256, 0, stream>>>(
      atomic_numbers, atom_mask, a_coef, a_exp, phi_c, phi_e, tabj, zaw, fiw,
      out, consts, n_atoms);
  zbl_edge_kernel<<<edge_blocks, 256, 0, stream>>>(
      disp, idx_i, idx_j, bmask, tabj, zaw, fiw, consts, out, n_edges,
      n_atoms);
}

// Round 7
// 47.571 us; speedup vs baseline: 1.0514x; 1.0514x over previous
//
#include <hip/hip_runtime.h>
#include <math.h>

#define LOG2E 1.4426950408889634f
#define NSLOT 512          // LDS window: atoms [key_base, key_base+512)
#define EPT   8            // edges per thread
#define EPB   (256 * EPT)  // 2048 edges per block

// Fully fused ZBL repulsion. Per block of 2048 consecutive edges:
//   consts  : recomputed uniformly from the 9 scalar inputs (cheap).
//   i-side  : za window staged in LDS from coalesced z/amask loads
//             (idx_i sorted => block spans ~32 atoms). i-factor
//             0.5*z_i*amask_i deferred to the sweep (exact distributivity).
//   j-side  : gather z[j] (4B) and compute za_j in-register.
//   reduce  : in-register run merge -> LDS atomics keyed rel. key_base ->
//             barrier -> sweep emits <=1 global atomic per touched atom.
//   Out-of-window keys fall back to guarded global atomics, so correctness
//   never depends on idx_i being sorted.
__global__ __launch_bounds__(256, 6) void zbl_fused_kernel(
    const float* __restrict__ z, const float* __restrict__ amask,
    const float* __restrict__ disp, const int* __restrict__ idx_i,
    const int* __restrict__ idx_j, const float* __restrict__ bmask,
    const float* __restrict__ a_coef, const float* __restrict__ a_exp,
    const float* __restrict__ phi_c, const float* __restrict__ phi_e,
    float* __restrict__ out, int n_edges, int n_atoms) {
  __shared__ float za_s[NSLOT];
  __shared__ float acc[NSLOT];
  const int t = threadIdx.x;
  const long bb = (long)blockIdx.x * EPB;
  const long Q = (long)blockIdx.x * 256 + t;  // global thread id
  const long e0 = Q * (long)EPT;

  // ---- uniform scalar constants (all-lane redundant, uniform -> SALU-ish)
  const float ae = fabsf(a_exp[0]);
  const float inv_a = 1.0f / fabsf(a_coef[0]);
  float cc0 = fabsf(phi_c[0]), cc1 = fabsf(phi_c[1]);
  float cc2 = fabsf(phi_c[2]), cc3 = fabsf(phi_c[3]);
  {
    float mx = fmaxf(fmaxf(cc0, cc1), fmaxf(cc2, cc3));
    cc0 = expf(cc0 - mx); cc1 = expf(cc1 - mx);
    cc2 = expf(cc2 - mx); cc3 = expf(cc3 - mx);
    float inv_s = 1.0f / (cc0 + cc1 + cc2 + cc3);
    cc0 *= inv_s; cc1 *= inv_s; cc2 *= inv_s; cc3 *= inv_s;
  }
  float q0 = fabsf(phi_e[0]) * LOG2E, q1 = fabsf(phi_e[1]) * LOG2E;
  float q2 = fabsf(phi_e[2]) * LOG2E, q3 = fabsf(phi_e[3]) * LOG2E;
  const float emin = fminf(fminf(q0, q1), fminf(q2, q3));
  // min term gets dd == 0 -> exp2(0) == 1 exactly (matches reference quirk:
  // max_log = -e_min*arg since arg >= 0; shift never added back).
  const float dd0 = (q0 - emin) * inv_a, dd1 = (q1 - emin) * inv_a;
  const float dd2 = (q2 - emin) * inv_a, dd3 = (q3 - emin) * inv_a;

  // ---- phase 1: issue global loads ----
  const int key_base = idx_i[bb];  // uniform broadcast load
  const int a0 = min(key_base + t, n_atoms - 1);
  const int a1 = min(key_base + t + 256, n_atoms - 1);
  const float zw0 = z[a0], zw1 = z[a1];      // window stage (coalesced)
  const float am0 = amask[a0], am1 = amask[a1];

  int kk[EPT];
  float dx[EPT], dy[EPT], dz[EPT], bm[EPT], zj[EPT];
  #pragma unroll
  for (int m = 0; m < EPT; ++m) { kk[m] = -1; dx[m] = dy[m] = dz[m] = bm[m] = 0.f; zj[m] = 1.f; }

  if (e0 + (EPT - 1) < (long)n_edges) {
    int4 I0 = ((const int4*)idx_i)[2 * Q];
    int4 I1 = ((const int4*)idx_i)[2 * Q + 1];
    int4 J0 = ((const int4*)idx_j)[2 * Q];
    int4 J1 = ((const int4*)idx_j)[2 * Q + 1];
    const float4* d4 = (const float4*)disp;
    float4 D0 = d4[6 * Q + 0], D1 = d4[6 * Q + 1], D2 = d4[6 * Q + 2];
    float4 D3 = d4[6 * Q + 3], D4 = d4[6 * Q + 4], D5 = d4[6 * Q + 5];
    float4 B0 = ((const float4*)bmask)[2 * Q];
    float4 B1 = ((const float4*)bmask)[2 * Q + 1];
    // j-gathers (4B each), all independent
    zj[0] = z[J0.x]; zj[1] = z[J0.y]; zj[2] = z[J0.z]; zj[3] = z[J0.w];
    zj[4] = z[J1.x]; zj[5] = z[J1.y]; zj[6] = z[J1.z]; zj[7] = z[J1.w];
    kk[0] = I0.x; kk[1] = I0.y; kk[2] = I0.z; kk[3] = I0.w;
    kk[4] = I1.x; kk[5] = I1.y; kk[6] = I1.z; kk[7] = I1.w;
    dx[0] = D0.x; dy[0] = D0.y; dz[0] = D0.z;
    dx[1] = D0.w; dy[1] = D1.x; dz[1] = D1.y;
    dx[2] = D1.z; dy[2] = D1.w; dz[2] = D2.x;
    dx[3] = D2.y; dy[3] = D2.z; dz[3] = D2.w;
    dx[4] = D3.x; dy[4] = D3.y; dz[4] = D3.z;
    dx[5] = D3.w; dy[5] = D4.x; dz[5] = D4.y;
    dx[6] = D4.z; dy[6] = D4.w; dz[6] = D5.x;
    dx[7] = D5.y; dy[7] = D5.z; dz[7] = D5.w;
    bm[0] = B0.x; bm[1] = B0.y; bm[2] = B0.z; bm[3] = B0.w;
    bm[4] = B1.x; bm[5] = B1.y; bm[6] = B1.z; bm[7] = B1.w;
  } else {
    #pragma unroll
    for (int m = 0; m < EPT; ++m) {
      const long e = e0 + m;
      if (e < (long)n_edges) {
        kk[m] = idx_i[e];
        zj[m] = z[idx_j[e]];
        dx[m] = disp[3 * e]; dy[m] = disp[3 * e + 1]; dz[m] = disp[3 * e + 2];
        bm[m] = bmask[e];
      }
    }
  }

  // ---- LDS stage: za window + acc zero ----
  acc[t] = 0.0f;
  acc[t + 256] = 0.0f;
  za_s[t] = __builtin_amdgcn_exp2f(ae * __builtin_amdgcn_logf(zw0));
  za_s[t + 256] = __builtin_amdgcn_exp2f(ae * __builtin_amdgcn_logf(zw1));
  const float fi0 = 0.5f * zw0 * am0;  // sweep factors (i-side, deferred)
  const float fi1 = 0.5f * zw1 * am1;
  __syncthreads();

  // ---- phase 2: per-edge values (pure ALU + LDS broadcast reads) ----
  float vv[EPT];
  #pragma unroll
  for (int m = 0; m < EPT; ++m) {
    float za_i;
    {
      int s = kk[m] - key_base;
      if ((unsigned)s < (unsigned)NSLOT) za_i = za_s[s];
      else if (kk[m] >= 0)  // out-of-window fallback (unsorted pathological)
        za_i = __builtin_amdgcn_exp2f(ae * __builtin_amdgcn_logf(z[kk[m]]));
      else za_i = 0.0f;
    }
    float n2 = fmaxf(dx[m] * dx[m] + dy[m] * dy[m] + dz[m] * dz[m], 1e-20f);
    float r = __builtin_amdgcn_rsqf(n2);  // 1/d
    float d = n2 * r;                     // d = sqrt(n2)
    float x = 5.0f - d;
    float poly = ((6.0f * x - 15.0f) * x + 10.0f) * x * x * x;
    float sw = (d < 4.0f) ? 1.0f : ((d >= 5.0f) ? 0.0f : poly);
    float zaj = __builtin_amdgcn_exp2f(ae * __builtin_amdgcn_logf(zj[m]));
    float qq = d * fmaxf(za_i + zaj, 1e-10f);
    float phi = cc0 * __builtin_amdgcn_exp2f(-dd0 * qq)
              + cc1 * __builtin_amdgcn_exp2f(-dd1 * qq)
              + cc2 * __builtin_amdgcn_exp2f(-dd2 * qq)
              + cc3 * __builtin_amdgcn_exp2f(-dd3 * qq);
    // i-factor (0.5*z_i*amask_i) deferred to sweep
    vv[m] = zj[m] * r * fmaxf(phi, 1e-30f) * fmaxf(sw, 1e-30f) * bm[m];
  }

  auto flush = [&](int key, float s) {
    if (key < 0) return;
    int slot = key - key_base;
    if ((unsigned)slot < (unsigned)NSLOT) {
      atomicAdd(&acc[slot], s);
    } else {  // rare fallback: apply i-factor directly
      atomicAdd(&out[key], s * 0.5f * z[key] * amask[key]);
    }
  };

  // ---- in-register merge of equal-adjacent keys ----
  {
    int cur = kk[0];
    float s = vv[0];
    #pragma unroll
    for (int m = 1; m < EPT; ++m) {
      if (kk[m] == cur) s += vv[m];
      else { flush(cur, s); cur = kk[m]; s = vv[m]; }
    }
    flush(cur, s);
  }

  __syncthreads();  // all LDS accumulation done

  // ---- sweep: one global atomic per touched atom ----
  {
    float val = acc[t];
    if (val != 0.0f) atomicAdd(&out[key_base + t], val * fi0);
    val = acc[t + 256];
    if (val != 0.0f) atomicAdd(&out[key_base + t + 256], val * fi1);
  }
}

extern "C" void kernel_launch(void* const* d_in, const int* in_sizes, int n_in,
                              void* d_out, int out_size, void* d_ws,
                              size_t ws_size, hipStream_t stream) {
  const float* atomic_numbers = (const float*)d_in[0];
  const float* disp           = (const float*)d_in[1];
  const int*   idx_i          = (const int*)d_in[2];
  const int*   idx_j          = (const int*)d_in[3];
  const float* atom_mask      = (const float*)d_in[4];
  // d_in[5] = batch_segments (unused), d_in[7] = batch_size (unused)
  const float* bmask          = (const float*)d_in[6];
  const float* a_coef         = (const float*)d_in[8];
  const float* a_exp          = (const float*)d_in[9];
  const float* phi_c          = (const float*)d_in[10];
  const float* phi_e          = (const float*)d_in[11];

  int n_atoms = in_sizes[0];
  int n_edges = in_sizes[2];

  float* out = (float*)d_out;

  hipMemsetAsync(out, 0, (size_t)out_size * sizeof(float), stream);

  int edge_blocks = (int)(((long)n_edges + EPB - 1) / EPB);
  zbl_fused_kernel<<<edge_blocks, 256, 0, stream>>>(
      atomic_numbers, atom_mask, disp, idx_i, idx_j, bmask, a_coef, a_exp,
      phi_c, phi_e, out, n_edges, n_atoms);
}

// Round 8
// 47.520 us; speedup vs baseline: 1.0525x; 1.0011x over previous
//
#include <hip/hip_runtime.h>
#include <math.h>

#define LOG2E 1.4426950408889634f
#define NSLOT 512          // LDS window: atoms [key_base, key_base+512)
#define EPT   8            // edges per thread
#define EPB   (256 * EPT)  // 2048 edges per block

// Fully fused ZBL repulsion. Per block of 2048 consecutive edges:
//   consts  : recomputed uniformly from the 9 scalar inputs (cheap).
//   i-side  : za window staged in LDS from coalesced z/amask loads
//             (idx_i sorted => block spans ~32 atoms). i-factor
//             0.5*z_i*amask_i deferred to the sweep (exact distributivity).
//   j-side  : gather z[j] (4B) and compute za_j in-register.
//   reduce  : in-register run merge -> LDS atomics keyed rel. key_base ->
//             barrier -> sweep emits <=1 global atomic per touched atom.
//   Out-of-window keys fall back to guarded global atomics, so correctness
//   never depends on idx_i being sorted.
//
// __launch_bounds__(256, 4): deliberately allow up to ~128 VGPRs so the
// entire phase-1 load batch (~20 VMEM, ~52 dest VGPRs) stays live — R5/R6/R7
// showed that tighter occupancy bounds make the allocator re-serialize the
// batch into dependent round-trips (VGPR=40/24/20), which is the bottleneck.
__global__ __launch_bounds__(256, 4) void zbl_fused_kernel(
    const float* __restrict__ z, const float* __restrict__ amask,
    const float* __restrict__ disp, const int* __restrict__ idx_i,
    const int* __restrict__ idx_j, const float* __restrict__ bmask,
    const float* __restrict__ a_coef, const float* __restrict__ a_exp,
    const float* __restrict__ phi_c, const float* __restrict__ phi_e,
    float* __restrict__ out, int n_edges, int n_atoms) {
  __shared__ float za_s[NSLOT];
  __shared__ float acc[NSLOT];
  const int t = threadIdx.x;
  const long bb = (long)blockIdx.x * EPB;
  const long Q = (long)blockIdx.x * 256 + t;  // global thread id
  const long e0 = Q * (long)EPT;

  // ---- uniform scalar constants (all-lane redundant, cheap)
  const float ae = fabsf(a_exp[0]);
  const float inv_a = 1.0f / fabsf(a_coef[0]);
  float cc0 = fabsf(phi_c[0]), cc1 = fabsf(phi_c[1]);
  float cc2 = fabsf(phi_c[2]), cc3 = fabsf(phi_c[3]);
  {
    float mx = fmaxf(fmaxf(cc0, cc1), fmaxf(cc2, cc3));
    cc0 = expf(cc0 - mx); cc1 = expf(cc1 - mx);
    cc2 = expf(cc2 - mx); cc3 = expf(cc3 - mx);
    float inv_s = 1.0f / (cc0 + cc1 + cc2 + cc3);
    cc0 *= inv_s; cc1 *= inv_s; cc2 *= inv_s; cc3 *= inv_s;
  }
  float q0 = fabsf(phi_e[0]) * LOG2E, q1 = fabsf(phi_e[1]) * LOG2E;
  float q2 = fabsf(phi_e[2]) * LOG2E, q3 = fabsf(phi_e[3]) * LOG2E;
  const float emin = fminf(fminf(q0, q1), fminf(q2, q3));
  // min term gets dd == 0 -> exp2(0) == 1 exactly (matches reference quirk:
  // max_log = -e_min*arg since arg >= 0; shift never added back).
  const float dd0 = (q0 - emin) * inv_a, dd1 = (q1 - emin) * inv_a;
  const float dd2 = (q2 - emin) * inv_a, dd3 = (q3 - emin) * inv_a;

  // ---- phase 1: issue ALL global loads as one flat batch ----
  const int key_base = idx_i[bb];  // uniform broadcast load
  const int a0 = min(key_base + t, n_atoms - 1);
  const int a1 = min(key_base + t + 256, n_atoms - 1);
  const float zw0 = z[a0], zw1 = z[a1];      // window stage (coalesced)
  const float am0 = amask[a0], am1 = amask[a1];

  int kk[EPT];
  float dx[EPT], dy[EPT], dz[EPT], bm[EPT], zj[EPT];
  #pragma unroll
  for (int m = 0; m < EPT; ++m) { kk[m] = -1; dx[m] = dy[m] = dz[m] = bm[m] = 0.f; zj[m] = 1.f; }

  if (e0 + (EPT - 1) < (long)n_edges) {
    int4 I0 = ((const int4*)idx_i)[2 * Q];
    int4 I1 = ((const int4*)idx_i)[2 * Q + 1];
    int4 J0 = ((const int4*)idx_j)[2 * Q];
    int4 J1 = ((const int4*)idx_j)[2 * Q + 1];
    const float4* d4 = (const float4*)disp;
    float4 D0 = d4[6 * Q + 0], D1 = d4[6 * Q + 1], D2 = d4[6 * Q + 2];
    float4 D3 = d4[6 * Q + 3], D4 = d4[6 * Q + 4], D5 = d4[6 * Q + 5];
    float4 B0 = ((const float4*)bmask)[2 * Q];
    float4 B1 = ((const float4*)bmask)[2 * Q + 1];
    // j-gathers (4B each), all independent
    zj[0] = z[J0.x]; zj[1] = z[J0.y]; zj[2] = z[J0.z]; zj[3] = z[J0.w];
    zj[4] = z[J1.x]; zj[5] = z[J1.y]; zj[6] = z[J1.z]; zj[7] = z[J1.w];
    kk[0] = I0.x; kk[1] = I0.y; kk[2] = I0.z; kk[3] = I0.w;
    kk[4] = I1.x; kk[5] = I1.y; kk[6] = I1.z; kk[7] = I1.w;
    dx[0] = D0.x; dy[0] = D0.y; dz[0] = D0.z;
    dx[1] = D0.w; dy[1] = D1.x; dz[1] = D1.y;
    dx[2] = D1.z; dy[2] = D1.w; dz[2] = D2.x;
    dx[3] = D2.y; dy[3] = D2.z; dz[3] = D2.w;
    dx[4] = D3.x; dy[4] = D3.y; dz[4] = D3.z;
    dx[5] = D3.w; dy[5] = D4.x; dz[5] = D4.y;
    dx[6] = D4.z; dy[6] = D4.w; dz[6] = D5.x;
    dx[7] = D5.y; dy[7] = D5.z; dz[7] = D5.w;
    bm[0] = B0.x; bm[1] = B0.y; bm[2] = B0.z; bm[3] = B0.w;
    bm[4] = B1.x; bm[5] = B1.y; bm[6] = B1.z; bm[7] = B1.w;
  } else {
    #pragma unroll
    for (int m = 0; m < EPT; ++m) {
      const long e = e0 + m;
      if (e < (long)n_edges) {
        kk[m] = idx_i[e];
        zj[m] = z[idx_j[e]];
        dx[m] = disp[3 * e]; dy[m] = disp[3 * e + 1]; dz[m] = disp[3 * e + 2];
        bm[m] = bmask[e];
      }
    }
  }

  // ---- LDS stage: za window + acc zero ----
  acc[t] = 0.0f;
  acc[t + 256] = 0.0f;
  za_s[t] = __builtin_amdgcn_exp2f(ae * __builtin_amdgcn_logf(zw0));
  za_s[t + 256] = __builtin_amdgcn_exp2f(ae * __builtin_amdgcn_logf(zw1));
  const float fi0 = 0.5f * zw0 * am0;  // sweep factors (i-side, deferred)
  const float fi1 = 0.5f * zw1 * am1;
  __syncthreads();

  // ---- phase 2: per-edge values (pure ALU + LDS broadcast reads) ----
  float vv[EPT];
  #pragma unroll
  for (int m = 0; m < EPT; ++m) {
    float za_i;
    {
      int s = kk[m] - key_base;
      if ((unsigned)s < (unsigned)NSLOT) za_i = za_s[s];
      else if (kk[m] >= 0)  // out-of-window fallback (unsorted pathological)
        za_i = __builtin_amdgcn_exp2f(ae * __builtin_amdgcn_logf(z[kk[m]]));
      else za_i = 0.0f;
    }
    float n2 = fmaxf(dx[m] * dx[m] + dy[m] * dy[m] + dz[m] * dz[m], 1e-20f);
    float r = __builtin_amdgcn_rsqf(n2);  // 1/d
    float d = n2 * r;                     // d = sqrt(n2)
    float x = 5.0f - d;
    float poly = ((6.0f * x - 15.0f) * x + 10.0f) * x * x * x;
    float sw = (d < 4.0f) ? 1.0f : ((d >= 5.0f) ? 0.0f : poly);
    float zaj = __builtin_amdgcn_exp2f(ae * __builtin_amdgcn_logf(zj[m]));
    float qq = d * fmaxf(za_i + zaj, 1e-10f);
    float phi = cc0 * __builtin_amdgcn_exp2f(-dd0 * qq)
              + cc1 * __builtin_amdgcn_exp2f(-dd1 * qq)
              + cc2 * __builtin_amdgcn_exp2f(-dd2 * qq)
              + cc3 * __builtin_amdgcn_exp2f(-dd3 * qq);
    // i-factor (0.5*z_i*amask_i) deferred to sweep
    vv[m] = zj[m] * r * fmaxf(phi, 1e-30f) * fmaxf(sw, 1e-30f) * bm[m];
  }

  auto flush = [&](int key, float s) {
    if (key < 0) return;
    int slot = key - key_base;
    if ((unsigned)slot < (unsigned)NSLOT) {
      atomicAdd(&acc[slot], s);
    } else {  // rare fallback: apply i-factor directly
      atomicAdd(&out[key], s * 0.5f * z[key] * amask[key]);
    }
  };

  // ---- in-register merge of equal-adjacent keys ----
  {
    int cur = kk[0];
    float s = vv[0];
    #pragma unroll
    for (int m = 1; m < EPT; ++m) {
      if (kk[m] == cur) s += vv[m];
      else { flush(cur, s); cur = kk[m]; s = vv[m]; }
    }
    flush(cur, s);
  }

  __syncthreads();  // all LDS accumulation done

  // ---- sweep: one global atomic per touched atom ----
  {
    float val = acc[t];
    if (val != 0.0f) atomicAdd(&out[key_base + t], val * fi0);
    val = acc[t + 256];
    if (val != 0.0f) atomicAdd(&out[key_base + t + 256], val * fi1);
  }
}

extern "C" void kernel_launch(void* const* d_in, const int* in_sizes, int n_in,
                              void* d_out, int out_size, void* d_ws,
                              size_t ws_size, hipStream_t stream) {
  const float* atomic_numbers = (const float*)d_in[0];
  const float* disp           = (const float*)d_in[1];
  const int*   idx_i          = (const int*)d_in[2];
  const int*   idx_j          = (const int*)d_in[3];
  const float* atom_mask      = (const float*)d_in[4];
  // d_in[5] = batch_segments (unused), d_in[7] = batch_size (unused)
  const float* bmask          = (const float*)d_in[6];
  const float* a_coef         = (const float*)d_in[8];
  const float* a_exp          = (const float*)d_in[9];
  const float* phi_c          = (const float*)d_in[10];
  const float* phi_e          = (const float*)d_in[11];

  int n_atoms = in_sizes[0];
  int n_edges = in_sizes[2];

  float* out = (float*)d_out;

  hipMemsetAsync(out, 0, (size_t)out_size * sizeof(float), stream);

  int edge_blocks = (int)(((long)n_edges + EPB - 1) / EPB);
  zbl_fused_kernel<<<edge_blocks, 256, 0, stream>>>(
      atomic_numbers, atom_mask, disp, idx_i, idx_j, bmask, a_coef, a_exp,
      phi_c, phi_e, out, n_edges, n_atoms);
}